// Round 4
// baseline (244.381 us; speedup 1.0000x reference)
//
#include <hip/hip_runtime.h>

// ============================================================================
// R16: zero-barrier j-split AT 4 WAVES/SIMD (R15 retained only 2/SIMD).
// A/B evidence: R13 (4 w/SIMD, 24 barriers) = 109us; R15 (2 w/SIMD, 0
// barriers) = 127us; VALU-busy ~50us in both -> stall is dependency latency,
// TLP dominates. This version gets BOTH: weights are NOT staged in LDS
// (they're 64KB total, L2/L3-resident, frag reads are 1KB-coalesced) ->
// LDS = 37888 B -> 4 blocks/CU -> 16 waves/CU, zero barriers in the loop.
// Structure: 256 threads / 4 waves; wave w owns j-rows [32w,32w+32)
// (j0=32w+l15, j1=j0+16) x ALL 128 fo; TJ=128, 4 p-iters.
// Math identical to R13/R15 (CM-scaled silu algebra; same prep kernel).
//
// __launch_bounds__ 2nd-arg EMPIRICAL RULE (this toolchain, gfx950):
//   (256,4)/(512,4) -> 64-VGPR cap, catastrophic spill. (256,2) safe.
// ============================================================================

#define B_ 2
#define N_ 512
#define F_ 128
#define TJ 128      // j-rows per tile (32 per wave)
#define MSTRIDE 136 // shorts per LDS row: 128 + 8 pad (16B-aligned rows)

#define CM   (-1.44269504088896340736f)   // -log2(e)
#define INVC (-0.69314718055994530942f)   // 1/CM = -ln2

typedef __attribute__((ext_vector_type(8))) short short8;
typedef __attribute__((ext_vector_type(4))) float floatx4;
typedef __attribute__((ext_vector_type(2))) float floatx2;

#if defined(__has_builtin)
#if __has_builtin(__builtin_amdgcn_exp2f)
#define EXP2F(x) __builtin_amdgcn_exp2f(x)
#endif
#endif
#ifndef EXP2F
#define EXP2F(x) __expf((x) * 0.69314718055994530942f)
#endif

__device__ __forceinline__ float fsilu(float x) {  // tail-only
    float e = __expf(-x);
    return x * __builtin_amdgcn_rcpf(1.0f + e);
}
__device__ __forceinline__ floatx2 mk2(float a, float b) {
    floatx2 r; r.x = a; r.y = b; return r;
}
// y = CM*x. Returns CM*silu(x), pairwise. 1 trans + packable full-rate ops.
__device__ __forceinline__ floatx2 silu2s(floatx2 y) {
    floatx2 e;
    e.x = EXP2F(y.x);              // = exp(-x)
    e.y = EXP2F(y.y);
    floatx2 d = e + 1.0f;
    floatx2 r;
    r.x = __uint_as_float(0x7EF311C3u - __float_as_uint(d.x));
    r.y = __uint_as_float(0x7EF311C3u - __float_as_uint(d.y));
    r = r * (2.0f - d * r);
    r = r * (2.0f - d * r);
    return y * r;                  // y * sigmoid(x) = CM * silu(x)
}
__device__ __forceinline__ unsigned cvtpk(float lo, float hi) {
    unsigned r;
    asm("v_cvt_pk_bf16_f32 %0, %1, %2" : "=v"(r) : "v"(lo), "v"(hi));
    return r;
}
// pack two floats to bf16 pair via v_perm_b32 (prep kernel only)
__device__ __forceinline__ unsigned pack2(float a, float b) {
    return __builtin_amdgcn_perm(__float_as_uint(b) + 0x8000u,
                                 __float_as_uint(a) + 0x8000u, 0x07060302u);
}

// ---------------------------------------------------------------------------
// Prep (unchanged): blocks [0,128): Hs/Ht (8 rows each, PRE-SCALED by CM);
// [128,144): weight A-frag pack; [144,146): msum.
// ---------------------------------------------------------------------------
__global__ __launch_bounds__(256) void egcl_prep(
        const float* __restrict__ h, const float* __restrict__ mask,
        const float* __restrict__ ew1, const float* __restrict__ ew2,
        const float* __restrict__ cw1,
        float* __restrict__ Hs, float* __restrict__ Ht,
        unsigned short* __restrict__ W2P, unsigned short* __restrict__ WcP,
        float* __restrict__ msum) {
    __shared__ float sh[8][F_];
    const int blk = blockIdx.x, tid = threadIdx.x;
    if (blk < 128) {
        const int r0 = blk * 8;
        const int col = tid & 127, half = tid >> 7;
#pragma unroll
        for (int rr = 0; rr < 4; ++rr) {
            int row = rr * 2 + half;
            sh[row][col] = h[(r0 + row) * F_ + col] * mask[r0 + row];
        }
        __syncthreads();
        const float* W = ew1 + half * F_ * F_ + col;
        float acc[8] = {0.f, 0.f, 0.f, 0.f, 0.f, 0.f, 0.f, 0.f};
#pragma unroll 8
        for (int k = 0; k < F_; ++k) {
            float w = W[k * F_];
#pragma unroll
            for (int r = 0; r < 8; ++r) acc[r] += sh[r][k] * w;
        }
        float* dst = half ? Ht : Hs;
#pragma unroll
        for (int r = 0; r < 8; ++r) dst[(r0 + r) * F_ + col] = acc[r] * CM;
    } else if (blk < 144) {
        const int wsel = (blk - 128) >> 3;
        const int mt = (blk - 128) & 7;
        const float* src = wsel ? cw1 : ew2;
        unsigned short* dst = wsel ? WcP : W2P;
        const int ln = tid & 63, kk = tid >> 6;       // kk 0..3
        const int qq = ln >> 4, ll = ln & 15;
#pragma unroll
        for (int rep = 0; rep < 2; ++rep) {
            const int krow = kk * 32 + qq * 8 + rep * 4;
            float f0 = src[(krow + 0) * F_ + mt * 16 + ll];
            float f1 = src[(krow + 1) * F_ + mt * 16 + ll];
            float f2 = src[(krow + 2) * F_ + mt * 16 + ll];
            float f3 = src[(krow + 3) * F_ + mt * 16 + ll];
            uint2 u = make_uint2(pack2(f0, f1), pack2(f2, f3));
            *(uint2*)(dst + ((mt * 4 + kk) * 64 + ln) * 8 + rep * 4) = u;
        }
    } else {
        const int bb = blk - 144;
        float v = mask[bb * N_ + tid] + mask[bb * N_ + 256 + tid];
        v += __shfl_xor(v, 1);  v += __shfl_xor(v, 2);
        v += __shfl_xor(v, 4);  v += __shfl_xor(v, 8);
        v += __shfl_xor(v, 16); v += __shfl_xor(v, 32);
        const int wave = tid >> 6, lane = tid & 63;
        if (lane == 0) sh[0][wave] = v;
        __syncthreads();
        if (tid == 0) msum[bb] = sh[0][0] + sh[0][1] + sh[0][2] + sh[0][3];
    }
}

// LDS layout (bytes) — total 37888 (4 blocks/CU: 4*37888 = 151552 <= 163840).
#define L_MS   0        // 34816  m (bf16), 128 rows x 136 shorts, wave-private
#define L_HB   34816    // 512
#define L_W1R  35328    // 512
#define L_EB2  35840    // 512   eb2 * CM
#define L_CB1  36352    // 512   cb1 * CM
#define L_CW2  36864    // 512   cw2 * INVC
#define L_HIN  37376    // 512
#define L_TOTAL 37888
// Post-loop aliases inside ms (dead after post-loop barrier):
#define L_AGGP (L_MS + 0)     // 2048  per-wave agg partials [4][128]
#define L_CSP  (L_MS + 2048)  // 64    per-wave cs partials [4][3]
#define L_NP   (L_MS + 2112)  // 1024  node-L1 partials [256]
#define L_TL   (L_MS + 3136)  // 512
#define L_AGGT (L_MS + 3648)  // 512

// ---------------------------------------------------------------------------
// Main: 1024 blocks x 256 threads (4 waves); block = one (b,i). Wave w owns
// j-rows [32w, 32w+32): j0 = 32w + l15, j1 = j0 + 16. Zero barriers in the
// p-loop; ms rows are wave-private. Weight A-frags are read STRAIGHT FROM
// GLOBAL (W2P/WcP are 64KB total, L2/L3-resident, 1KB-coalesced per read;
// each frag feeds 2 MFMAs via the j0/j1 unroll).
// ---------------------------------------------------------------------------
__global__ __launch_bounds__(256, 2) void egcl_main(
        const float* __restrict__ h, const float* __restrict__ coord,
        const float* __restrict__ mask,
        const float* __restrict__ eb1, const float* __restrict__ eb2,
        const float* __restrict__ cb1, const float* __restrict__ cw2,
        const float* __restrict__ nw1, const float* __restrict__ nb1,
        const float* __restrict__ nw2, const float* __restrict__ nb2,
        const float* __restrict__ ew1,
        const float* __restrict__ Hs, const float* __restrict__ Ht,
        const unsigned short* __restrict__ W2P,
        const unsigned short* __restrict__ WcP,
        const float* __restrict__ msum,
        float* __restrict__ out_h, float* __restrict__ out_coord) {
    extern __shared__ char smem[];
    unsigned short* ms  = (unsigned short*)(smem + L_MS);
    float* HB    = (float*)(smem + L_HB);
    float* W1R   = (float*)(smem + L_W1R);
    float* EB2s  = (float*)(smem + L_EB2);
    float* CB1s  = (float*)(smem + L_CB1);
    float* CW2s  = (float*)(smem + L_CW2);
    float* hin   = (float*)(smem + L_HIN);
    float* aggp  = (float*)(smem + L_AGGP);
    float* csp   = (float*)(smem + L_CSP);
    float* np    = (float*)(smem + L_NP);
    float* tl    = (float*)(smem + L_TL);
    float* aggt  = (float*)(smem + L_AGGT);

    const int tid  = threadIdx.x;
    const int wave = tid >> 6, lane = tid & 63;
    const int q = lane >> 4, l15 = lane & 15;
    const int bi = blockIdx.x;
    const int b  = bi >> 9;
    const float mask_i = mask[bi];

    if (tid < F_) {
        HB[tid]   = Ht[bi * F_ + tid] + CM * eb1[tid];  // Ht pre-scaled (prep)
        W1R[tid]  = CM * ew1[2 * F_ * F_ + tid];
        EB2s[tid] = CM * eb2[tid];
        CB1s[tid] = CM * cb1[tid];
        CW2s[tid] = INVC * cw2[tid];
        hin[tid]  = h[bi * F_ + tid] * mask_i;
    }
    const float cmi0 = coord[bi * 3 + 0] * mask_i;
    const float cmi1 = coord[bi * 3 + 1] * mask_i;
    const float cmi2 = coord[bi * 3 + 2] * mask_i;
    __syncthreads();   // the ONLY pre-loop barrier

    const int j0 = wave * 32 + l15;         // local j-rows (fixed per lane)
    const int j1 = j0 + 16;
    unsigned short* msr0 = ms + j0 * MSTRIDE;
    unsigned short* msr1 = ms + j1 * MSTRIDE;

    floatx2 ag2[16];                        // agg partials: [s][pair]
#pragma unroll
    for (int t = 0; t < 16; ++t) ag2[t] = mk2(0.f, 0.f);
    float cs0 = 0.f, cs1 = 0.f, cs2 = 0.f;

    for (int p = 0; p < N_ / TJ; ++p) {
        const int jg0 = b * N_ + p * TJ + j0;
        const int jg1 = jg0 + 16;
        const float mj0 = mask[jg0], mj1 = mask[jg1];
        const float c00 = coord[jg0 * 3 + 0] * mj0;
        const float c01 = coord[jg0 * 3 + 1] * mj0;
        const float c02 = coord[jg0 * 3 + 2] * mj0;
        const float c10 = coord[jg1 * 3 + 0] * mj1;
        const float c11 = coord[jg1 * 3 + 1] * mj1;
        const float c12 = coord[jg1 * 3 + 2] * mj1;
        const float d00 = cmi0 - c00, d01 = cmi1 - c01, d02 = cmi2 - c02;
        const float d10 = cmi0 - c10, d11 = cmi1 - c11, d12 = cmi2 - c12;
        const float f2_0 = mask_i * mj0, f2_1 = mask_i * mj1;
        const float rad0 = (d00 * d00 + d01 * d01 + d02 * d02) * f2_0;
        const float rad1 = (d10 * d10 + d11 * d11 + d12 * d12) * f2_1;
        const floatx2 rr0 = mk2(rad0, rad0), rr1 = mk2(rad1, rad1);
        const floatx2 f220 = mk2(f2_0, f2_0), f221 = mk2(f2_1, f2_1);

        // ---- m1 build: both j-sets, directly into MFMA B-frags ----
        short8 bfr0[4], bfr1[4];
#pragma unroll
        for (int kk = 0; kk < 4; ++kk) {
            const int ko = kk * 32 + q * 8;
            floatx4 hb0 = *(const floatx4*)(HB + ko);
            floatx4 hb1 = *(const floatx4*)(HB + ko + 4);
            floatx4 w10 = *(const floatx4*)(W1R + ko);
            floatx4 w11 = *(const floatx4*)(W1R + ko + 4);
            {
                floatx4 hsA = *(const floatx4*)(Hs + jg0 * F_ + ko);
                floatx4 hsB = *(const floatx4*)(Hs + jg0 * F_ + ko + 4);
                floatx2 y0 = mk2(hsA[0], hsA[1]) + mk2(hb0[0], hb0[1]) + rr0 * mk2(w10[0], w10[1]);
                floatx2 y1 = mk2(hsA[2], hsA[3]) + mk2(hb0[2], hb0[3]) + rr0 * mk2(w10[2], w10[3]);
                floatx2 y2 = mk2(hsB[0], hsB[1]) + mk2(hb1[0], hb1[1]) + rr0 * mk2(w11[0], w11[1]);
                floatx2 y3 = mk2(hsB[2], hsB[3]) + mk2(hb1[2], hb1[3]) + rr0 * mk2(w11[2], w11[3]);
                floatx2 x0 = silu2s(y0), x1 = silu2s(y1);
                floatx2 x2 = silu2s(y2), x3 = silu2s(y3);
                union { short8 s8; unsigned u[4]; } pu;
                pu.u[0] = cvtpk(x0.x, x0.y); pu.u[1] = cvtpk(x1.x, x1.y);
                pu.u[2] = cvtpk(x2.x, x2.y); pu.u[3] = cvtpk(x3.x, x3.y);
                bfr0[kk] = pu.s8;
            }
            {
                floatx4 hsA = *(const floatx4*)(Hs + jg1 * F_ + ko);
                floatx4 hsB = *(const floatx4*)(Hs + jg1 * F_ + ko + 4);
                floatx2 y0 = mk2(hsA[0], hsA[1]) + mk2(hb0[0], hb0[1]) + rr1 * mk2(w10[0], w10[1]);
                floatx2 y1 = mk2(hsA[2], hsA[3]) + mk2(hb0[2], hb0[3]) + rr1 * mk2(w10[2], w10[3]);
                floatx2 y2 = mk2(hsB[0], hsB[1]) + mk2(hb1[0], hb1[1]) + rr1 * mk2(w11[0], w11[1]);
                floatx2 y3 = mk2(hsB[2], hsB[3]) + mk2(hb1[2], hb1[3]) + rr1 * mk2(w11[2], w11[3]);
                floatx2 x0 = silu2s(y0), x1 = silu2s(y1);
                floatx2 x2 = silu2s(y2), x3 = silu2s(y3);
                union { short8 s8; unsigned u[4]; } pu;
                pu.u[0] = cvtpk(x0.x, x0.y); pu.u[1] = cvtpk(x1.x, x1.y);
                pu.u[2] = cvtpk(x2.x, x2.y); pu.u[3] = cvtpk(x3.x, x3.y);
                bfr1[kk] = pu.s8;
            }
        }

        // ---- GEMM1 over 8 fo-blocks; A-frags from global (L2-resident) ----
#pragma unroll
        for (int s = 0; s < 8; ++s) {
            floatx4 bias = *(const floatx4*)(EB2s + s * 16 + q * 4);
            floatx4 a0 = bias, a1 = bias;
#pragma unroll
            for (int kk = 0; kk < 4; ++kk) {
                short8 wf = *(const short8*)(W2P + ((s * 4 + kk) * 64 + lane) * 8);
                a0 = __builtin_amdgcn_mfma_f32_16x16x32_bf16(wf, bfr0[kk], a0, 0, 0, 0);
                a1 = __builtin_amdgcn_mfma_f32_16x16x32_bf16(wf, bfr1[kk], a1, 0, 0, 0);
            }
            floatx2 p00 = silu2s(mk2(a0[0], a0[1])) * f220;
            floatx2 p01 = silu2s(mk2(a0[2], a0[3])) * f220;
            floatx2 p10 = silu2s(mk2(a1[0], a1[1])) * f221;
            floatx2 p11 = silu2s(mk2(a1[2], a1[3])) * f221;
            ag2[2 * s]     += p00 + p10;
            ag2[2 * s + 1] += p01 + p11;
            *(uint2*)(msr0 + s * 16 + q * 4) =
                make_uint2(cvtpk(p00.x, p00.y), cvtpk(p01.x, p01.y));
            *(uint2*)(msr1 + s * 16 + q * 4) =
                make_uint2(cvtpk(p10.x, p10.y), cvtpk(p11.x, p11.y));
        }

        // ---- GEMM2 over 8 fo2-blocks + embed (wave-private) ----
        short8 mfr0[4], mfr1[4];
#pragma unroll
        for (int kk = 0; kk < 4; ++kk) {
            mfr0[kk] = *(const short8*)(msr0 + kk * 32 + q * 8);
            mfr1[kk] = *(const short8*)(msr1 + kk * 32 + q * 8);
        }
        floatx2 esv0 = mk2(0.f, 0.f), esv1 = mk2(0.f, 0.f);
#pragma unroll
        for (int s = 0; s < 8; ++s) {
            floatx4 cb = *(const floatx4*)(CB1s + s * 16 + q * 4);
            floatx4 a0 = cb, a1 = cb;
#pragma unroll
            for (int kk = 0; kk < 4; ++kk) {
                short8 wf = *(const short8*)(WcP + ((s * 4 + kk) * 64 + lane) * 8);
                a0 = __builtin_amdgcn_mfma_f32_16x16x32_bf16(wf, mfr0[kk], a0, 0, 0, 0);
                a1 = __builtin_amdgcn_mfma_f32_16x16x32_bf16(wf, mfr1[kk], a1, 0, 0, 0);
            }
            floatx4 wv = *(const floatx4*)(CW2s + s * 16 + q * 4);  // *INVC
            esv0 += silu2s(mk2(a0[0], a0[1])) * mk2(wv[0], wv[1]);
            esv0 += silu2s(mk2(a0[2], a0[3])) * mk2(wv[2], wv[3]);
            esv1 += silu2s(mk2(a1[0], a1[1])) * mk2(wv[0], wv[1]);
            esv1 += silu2s(mk2(a1[2], a1[3])) * mk2(wv[2], wv[3]);
        }
        float es0 = esv0.x + esv0.y;
        float es1 = esv1.x + esv1.y;
        es0 += __shfl_xor(es0, 16); es0 += __shfl_xor(es0, 32);
        es1 += __shfl_xor(es1, 16); es1 += __shfl_xor(es1, 32);
        if (q == 0) {
            float w0 = es0 * f2_0 * f2_0;
            float w1 = es1 * f2_1 * f2_1;
            cs0 += d00 * w0 + d10 * w1;
            cs1 += d01 * w0 + d11 * w1;
            cs2 += d02 * w0 + d12 * w1;
        }
    }  // p — zero barriers

    // ---- in-wave reductions over j (l15) ----
#pragma unroll
    for (int t = 0; t < 16; ++t) {
        float vx = ag2[t].x, vy = ag2[t].y;
        vx += __shfl_xor(vx, 1); vx += __shfl_xor(vx, 2);
        vx += __shfl_xor(vx, 4); vx += __shfl_xor(vx, 8);
        vy += __shfl_xor(vy, 1); vy += __shfl_xor(vy, 2);
        vy += __shfl_xor(vy, 4); vy += __shfl_xor(vy, 8);
        ag2[t] = mk2(vx, vy);
    }
    cs0 += __shfl_xor(cs0, 1); cs0 += __shfl_xor(cs0, 2);
    cs0 += __shfl_xor(cs0, 4); cs0 += __shfl_xor(cs0, 8);
    cs1 += __shfl_xor(cs1, 1); cs1 += __shfl_xor(cs1, 2);
    cs1 += __shfl_xor(cs1, 4); cs1 += __shfl_xor(cs1, 8);
    cs2 += __shfl_xor(cs2, 1); cs2 += __shfl_xor(cs2, 2);
    cs2 += __shfl_xor(cs2, 4); cs2 += __shfl_xor(cs2, 8);

    __syncthreads();   // all waves done with ms -> safe to alias
    if (l15 == 0) {
#pragma unroll
        for (int s = 0; s < 8; ++s) {
            floatx4 o = {ag2[2 * s].x, ag2[2 * s].y,
                         ag2[2 * s + 1].x, ag2[2 * s + 1].y};
            *(floatx4*)(aggp + wave * F_ + s * 16 + q * 4) = o;
        }
    }
    if (lane == 0) {
        csp[wave * 3 + 0] = cs0;
        csp[wave * 3 + 1] = cs1;
        csp[wave * 3 + 2] = cs2;
    }
    __syncthreads();
    if (tid < F_)
        aggt[tid] = (aggp[tid] + aggp[F_ + tid] + aggp[2 * F_ + tid] +
                     aggp[3 * F_ + tid]) * (mask_i * INVC);   // unwind CM
    __syncthreads();
    // ---- node MLP layer 1 ----
    {
        int half = tid >> 7, col = tid & 127;
        const float* W = nw1 + half * 128 * F_ + col;
        float s = 0.f;
        if (half == 0) {
#pragma unroll 8
            for (int k = 0; k < F_; ++k) s += hin[k] * W[k * F_];
            s *= mask_i;
        } else {
#pragma unroll 8
            for (int k = 0; k < F_; ++k) s += aggt[k] * W[k * F_];
        }
        np[tid] = s;
    }
    __syncthreads();
    if (tid < F_) tl[tid] = fsilu(np[tid] + np[128 + tid] + nb1[tid]);
    __syncthreads();
    if (tid < F_) {
        float s = nb2[tid];
#pragma unroll 8
        for (int k = 0; k < F_; ++k) s += tl[k] * nw2[k * F_ + tid];
        out_h[bi * F_ + tid] = (hin[tid] + s) * mask_i;
    } else if (tid < F_ + 3) {
        int d = tid - F_;
        float denom = mask_i * msum[b] + 1e-10f;
        float cm = (d == 0) ? cmi0 : ((d == 1) ? cmi1 : cmi2);
        float cst = csp[d] + csp[3 + d] + csp[6 + d] + csp[9 + d];
        out_coord[bi * 3 + d] = (cm + cst * __builtin_amdgcn_rcpf(denom)) * mask_i;
    }
}

// ---------------------------------------------------------------------------
extern "C" void kernel_launch(void* const* d_in, const int* in_sizes, int n_in,
                              void* d_out, int out_size, void* d_ws, size_t ws_size,
                              hipStream_t stream) {
    const float* h     = (const float*)d_in[0];
    const float* coord = (const float*)d_in[1];
    const float* mask  = (const float*)d_in[2];
    const float* ew1   = (const float*)d_in[3];
    const float* eb1   = (const float*)d_in[4];
    const float* ew2   = (const float*)d_in[5];
    const float* eb2   = (const float*)d_in[6];
    const float* nw1   = (const float*)d_in[7];
    const float* nb1   = (const float*)d_in[8];
    const float* nw2   = (const float*)d_in[9];
    const float* nb2   = (const float*)d_in[10];
    const float* cw1   = (const float*)d_in[11];
    const float* cb1   = (const float*)d_in[12];
    const float* cw2   = (const float*)d_in[13];

    float* Hs = (float*)d_ws;                                   // 131072 f32
    float* Ht = Hs + B_ * N_ * F_;                              // 131072 f32
    unsigned short* W2P = (unsigned short*)(Ht + B_ * N_ * F_); // 16384 u16
    unsigned short* WcP = W2P + F_ * F_;                        // 16384 u16
    float* msum = (float*)(WcP + F_ * F_);                      // 2 f32

    float* out_h = (float*)d_out;
    float* out_coord = out_h + B_ * N_ * F_;

    egcl_prep<<<146, 256, 0, stream>>>(h, mask, ew1, ew2, cw1,
                                       Hs, Ht, W2P, WcP, msum);
    egcl_main<<<B_ * N_, 256, L_TOTAL, stream>>>(
        h, coord, mask, eb1, eb2, cb1, cw2, nw1, nb1, nw2, nb2, ew1,
        Hs, Ht, W2P, WcP, msum, out_h, out_coord);
}

// Round 5
// 216.227 us; speedup vs baseline: 1.1302x; 1.1302x over previous
//
#include <hip/hip_runtime.h>

// ============================================================================
// R17: mixed decomposition — GEMM1 j-split (m1 in regs, W2 from LDS),
// GEMM2 fo-split (Wc in regs), 2 barriers/tile, 16 waves/CU.
// Evidence: R13 (fo-split, 24 barriers, 16 w/CU) = 109us; R15 (j-split, 0
// barriers, 8 w/CU) = 127us; R16 (weights-from-global) = 176us w/ 47MB
// scratch spill (WRITE_SIZE) -> NEVER read weight frags from global in the
// inner loop. This version:
//   - 512 threads / 8 waves; wave w: j-rows [16w,16w+16) for GEMM1 (m1 built
//     straight into B-frag registers; no m1s LDS, no redundant build),
//     fo2-slice [16w,16w+16) for GEMM2 (wcf in 16 VGPRs, R13-verified path).
//   - W2 A-frags staged once into LDS (32KB, R15-verified path).
//   - ms transpose buffer MSTRIDE=144 (288B rows): b128 read conflict
//     8-way -> 4-way vs 136.
//   - LDS 75776 B -> 2 blocks/CU -> 16 waves/CU (4/SIMD), 8 barriers total.
// Math identical to R13/R15 (CM-scaled silu algebra; same prep kernel).
//
// __launch_bounds__ 2nd-arg EMPIRICAL RULE (this toolchain, gfx950):
//   2nd arg >= 4 -> 64-VGPR cap, catastrophic spill. (512,2) safe.
// ============================================================================

#define B_ 2
#define N_ 512
#define F_ 128
#define TJ 128      // j-rows per tile (16 per wave)
#define MSTRIDE 144 // shorts per ms row: 128 + 16 pad (288B, bank-spread)

#define CM   (-1.44269504088896340736f)   // -log2(e)
#define INVC (-0.69314718055994530942f)   // 1/CM = -ln2

typedef __attribute__((ext_vector_type(8))) short short8;
typedef __attribute__((ext_vector_type(4))) float floatx4;
typedef __attribute__((ext_vector_type(2))) float floatx2;

#if defined(__has_builtin)
#if __has_builtin(__builtin_amdgcn_exp2f)
#define EXP2F(x) __builtin_amdgcn_exp2f(x)
#endif
#endif
#ifndef EXP2F
#define EXP2F(x) __expf((x) * 0.69314718055994530942f)
#endif

__device__ __forceinline__ float fsilu(float x) {  // tail-only
    float e = __expf(-x);
    return x * __builtin_amdgcn_rcpf(1.0f + e);
}
__device__ __forceinline__ floatx2 mk2(float a, float b) {
    floatx2 r; r.x = a; r.y = b; return r;
}
// y = CM*x. Returns CM*silu(x), pairwise. 1 trans + packable full-rate ops.
__device__ __forceinline__ floatx2 silu2s(floatx2 y) {
    floatx2 e;
    e.x = EXP2F(y.x);              // = exp(-x)
    e.y = EXP2F(y.y);
    floatx2 d = e + 1.0f;
    floatx2 r;
    r.x = __uint_as_float(0x7EF311C3u - __float_as_uint(d.x));
    r.y = __uint_as_float(0x7EF311C3u - __float_as_uint(d.y));
    r = r * (2.0f - d * r);
    r = r * (2.0f - d * r);
    return y * r;                  // y * sigmoid(x) = CM * silu(x)
}
__device__ __forceinline__ unsigned cvtpk(float lo, float hi) {
    unsigned r;
    asm("v_cvt_pk_bf16_f32 %0, %1, %2" : "=v"(r) : "v"(lo), "v"(hi));
    return r;
}
// pack two floats to bf16 pair via v_perm_b32 (prep kernel only)
__device__ __forceinline__ unsigned pack2(float a, float b) {
    return __builtin_amdgcn_perm(__float_as_uint(b) + 0x8000u,
                                 __float_as_uint(a) + 0x8000u, 0x07060302u);
}

// ---------------------------------------------------------------------------
// Prep (unchanged): blocks [0,128): Hs/Ht (8 rows each, PRE-SCALED by CM);
// [128,144): weight A-frag pack; [144,146): msum.
// ---------------------------------------------------------------------------
__global__ __launch_bounds__(256) void egcl_prep(
        const float* __restrict__ h, const float* __restrict__ mask,
        const float* __restrict__ ew1, const float* __restrict__ ew2,
        const float* __restrict__ cw1,
        float* __restrict__ Hs, float* __restrict__ Ht,
        unsigned short* __restrict__ W2P, unsigned short* __restrict__ WcP,
        float* __restrict__ msum) {
    __shared__ float sh[8][F_];
    const int blk = blockIdx.x, tid = threadIdx.x;
    if (blk < 128) {
        const int r0 = blk * 8;
        const int col = tid & 127, half = tid >> 7;
#pragma unroll
        for (int rr = 0; rr < 4; ++rr) {
            int row = rr * 2 + half;
            sh[row][col] = h[(r0 + row) * F_ + col] * mask[r0 + row];
        }
        __syncthreads();
        const float* W = ew1 + half * F_ * F_ + col;
        float acc[8] = {0.f, 0.f, 0.f, 0.f, 0.f, 0.f, 0.f, 0.f};
#pragma unroll 8
        for (int k = 0; k < F_; ++k) {
            float w = W[k * F_];
#pragma unroll
            for (int r = 0; r < 8; ++r) acc[r] += sh[r][k] * w;
        }
        float* dst = half ? Ht : Hs;
#pragma unroll
        for (int r = 0; r < 8; ++r) dst[(r0 + r) * F_ + col] = acc[r] * CM;
    } else if (blk < 144) {
        const int wsel = (blk - 128) >> 3;
        const int mt = (blk - 128) & 7;
        const float* src = wsel ? cw1 : ew2;
        unsigned short* dst = wsel ? WcP : W2P;
        const int ln = tid & 63, kk = tid >> 6;       // kk 0..3
        const int qq = ln >> 4, ll = ln & 15;
#pragma unroll
        for (int rep = 0; rep < 2; ++rep) {
            const int krow = kk * 32 + qq * 8 + rep * 4;
            float f0 = src[(krow + 0) * F_ + mt * 16 + ll];
            float f1 = src[(krow + 1) * F_ + mt * 16 + ll];
            float f2 = src[(krow + 2) * F_ + mt * 16 + ll];
            float f3 = src[(krow + 3) * F_ + mt * 16 + ll];
            uint2 u = make_uint2(pack2(f0, f1), pack2(f2, f3));
            *(uint2*)(dst + ((mt * 4 + kk) * 64 + ln) * 8 + rep * 4) = u;
        }
    } else {
        const int bb = blk - 144;
        float v = mask[bb * N_ + tid] + mask[bb * N_ + 256 + tid];
        v += __shfl_xor(v, 1);  v += __shfl_xor(v, 2);
        v += __shfl_xor(v, 4);  v += __shfl_xor(v, 8);
        v += __shfl_xor(v, 16); v += __shfl_xor(v, 32);
        const int wave = tid >> 6, lane = tid & 63;
        if (lane == 0) sh[0][wave] = v;
        __syncthreads();
        if (tid == 0) msum[bb] = sh[0][0] + sh[0][1] + sh[0][2] + sh[0][3];
    }
}

// LDS layout (bytes) — total 75776 (x2 = 151552 <= 163840 -> 2 blocks/CU).
#define L_W2   0        // 32768  W2 A-frags (bf16, 128x128)
#define L_MS   32768    // 36864  m (bf16), 128 rows x 144 shorts
#define L_EMBP 69632    // 4096   embed partials [8 waves][128 j]
#define L_HB   73728    // 512
#define L_W1R  74240    // 512
#define L_EB2  74752    // 512   eb2 * CM
#define L_HIN  75264    // 512
#define L_TOTAL 75776
// Post-loop aliases inside ms (dead after post-loop barrier):
#define L_AGGP (L_MS + 0)     // 4096  per-wave agg partials [8][128]
#define L_CSP  (L_MS + 4096)  // 128   per-wave cs partials [8][3]
#define L_NP   (L_MS + 4224)  // 2048  node-L1 partials [512]
#define L_TL   (L_MS + 6272)  // 512
#define L_AGGT (L_MS + 6784)  // 512

// ---------------------------------------------------------------------------
// Main: 1024 blocks x 512 threads (8 waves); block = one (b,i).
// Per tile (TJ=128):
//   phase1: wave w builds m1 B-frags for j-rows [16w,16w+16) in REGISTERS.
//   GEMM1 (j-split): A = W2 frags from LDS, all 8 fo-blocks; epilogue silu,
//                    agg accumulate, write ms rows [16w,16w+16).
//   --- barrier A (ms visible) ---
//   GEMM2 (fo-split): wave w owns fo2 [16w,16w+16), wcf in regs; B = ms
//                    frags for all 8 j-sets; embed partials -> embp[w][j].
//   --- barrier B (embp visible; guards ms for next tile) ---
//   coord: wave w accumulates cs for its own j-rows (d/f2 still in regs).
// ---------------------------------------------------------------------------
__global__ __launch_bounds__(512, 2) void egcl_main(
        const float* __restrict__ h, const float* __restrict__ coord,
        const float* __restrict__ mask,
        const float* __restrict__ eb1, const float* __restrict__ eb2,
        const float* __restrict__ cb1, const float* __restrict__ cw2,
        const float* __restrict__ nw1, const float* __restrict__ nb1,
        const float* __restrict__ nw2, const float* __restrict__ nb2,
        const float* __restrict__ ew1,
        const float* __restrict__ Hs, const float* __restrict__ Ht,
        const unsigned short* __restrict__ W2P,
        const unsigned short* __restrict__ WcP,
        const float* __restrict__ msum,
        float* __restrict__ out_h, float* __restrict__ out_coord) {
    extern __shared__ char smem[];
    unsigned short* W2L = (unsigned short*)(smem + L_W2);
    unsigned short* ms  = (unsigned short*)(smem + L_MS);
    float* embp  = (float*)(smem + L_EMBP);
    float* HB    = (float*)(smem + L_HB);
    float* W1R   = (float*)(smem + L_W1R);
    float* EB2s  = (float*)(smem + L_EB2);
    float* hin   = (float*)(smem + L_HIN);
    float* aggp  = (float*)(smem + L_AGGP);
    float* csp   = (float*)(smem + L_CSP);
    float* np    = (float*)(smem + L_NP);
    float* tl    = (float*)(smem + L_TL);
    float* aggt  = (float*)(smem + L_AGGT);

    const int tid  = threadIdx.x;
    const int wave = tid >> 6, lane = tid & 63;
    const int q = lane >> 4, l15 = lane & 15;
    const int bi = blockIdx.x;
    const int b  = bi >> 9;
    const float mask_i = mask[bi];

    // ---- stage W2 A-frags (32768 B) into LDS ----
    {
        const uint4* s2 = (const uint4*)W2P;   // 2048 uint4
        uint4* d2 = (uint4*)(smem + L_W2);
#pragma unroll
        for (int t = 0; t < 4; ++t) d2[tid + t * 512] = s2[tid + t * 512];
    }
    if (tid < F_) {
        HB[tid]   = Ht[bi * F_ + tid] + CM * eb1[tid];  // Ht pre-scaled (prep)
        W1R[tid]  = CM * ew1[2 * F_ * F_ + tid];
        EB2s[tid] = CM * eb2[tid];
        hin[tid]  = h[bi * F_ + tid] * mask_i;
    }
    const float cmi0 = coord[bi * 3 + 0] * mask_i;
    const float cmi1 = coord[bi * 3 + 1] * mask_i;
    const float cmi2 = coord[bi * 3 + 2] * mask_i;

    // ---- per-wave GEMM2 constants: fo2-slice [16*wave, 16*wave+16) ----
    short8 wcf[4];
#pragma unroll
    for (int kk = 0; kk < 4; ++kk)
        wcf[kk] = *(const short8*)(WcP + ((wave * 4 + kk) * 64 + lane) * 8);
    const floatx4 c1b = (*(const floatx4*)(cb1 + wave * 16 + q * 4)) * CM;
    floatx2 w2c2[2];
    {
        floatx4 wv = *(const floatx4*)(cw2 + wave * 16 + q * 4);
        w2c2[0] = mk2(wv[0], wv[1]) * INVC;
        w2c2[1] = mk2(wv[2], wv[3]) * INVC;
    }
    __syncthreads();

    const int jl = wave * 16 + l15;         // own j-row (fixed per lane)
    unsigned short* msr = ms + jl * MSTRIDE;

    floatx2 ag2[16];                        // agg partials over own j
#pragma unroll
    for (int t = 0; t < 16; ++t) ag2[t] = mk2(0.f, 0.f);
    float cs0 = 0.f, cs1 = 0.f, cs2 = 0.f;

    for (int p = 0; p < N_ / TJ; ++p) {
        const int jg = b * N_ + p * TJ + jl;
        const float mj = mask[jg];
        const float c0 = coord[jg * 3 + 0] * mj;
        const float c1 = coord[jg * 3 + 1] * mj;
        const float c2 = coord[jg * 3 + 2] * mj;
        const float d0 = cmi0 - c0, d1 = cmi1 - c1, d2 = cmi2 - c2;
        const float f2 = mask_i * mj;
        const float rad = (d0 * d0 + d1 * d1 + d2 * d2) * f2;
        const floatx2 rr = mk2(rad, rad);
        const floatx2 f22 = mk2(f2, f2);

        // ---- phase1: m1 build, directly into MFMA B-frags (registers) ----
        short8 bfr[4];
#pragma unroll
        for (int kk = 0; kk < 4; ++kk) {
            const int ko = kk * 32 + q * 8;
            floatx4 hb0 = *(const floatx4*)(HB + ko);
            floatx4 hb1 = *(const floatx4*)(HB + ko + 4);
            floatx4 w10 = *(const floatx4*)(W1R + ko);
            floatx4 w11 = *(const floatx4*)(W1R + ko + 4);
            floatx4 hsA = *(const floatx4*)(Hs + jg * F_ + ko);
            floatx4 hsB = *(const floatx4*)(Hs + jg * F_ + ko + 4);
            floatx2 y0 = mk2(hsA[0], hsA[1]) + mk2(hb0[0], hb0[1]) + rr * mk2(w10[0], w10[1]);
            floatx2 y1 = mk2(hsA[2], hsA[3]) + mk2(hb0[2], hb0[3]) + rr * mk2(w10[2], w10[3]);
            floatx2 y2 = mk2(hsB[0], hsB[1]) + mk2(hb1[0], hb1[1]) + rr * mk2(w11[0], w11[1]);
            floatx2 y3 = mk2(hsB[2], hsB[3]) + mk2(hb1[2], hb1[3]) + rr * mk2(w11[2], w11[3]);
            floatx2 x0 = silu2s(y0), x1 = silu2s(y1);
            floatx2 x2 = silu2s(y2), x3 = silu2s(y3);
            union { short8 s8; unsigned u[4]; } pu;
            pu.u[0] = cvtpk(x0.x, x0.y); pu.u[1] = cvtpk(x1.x, x1.y);
            pu.u[2] = cvtpk(x2.x, x2.y); pu.u[3] = cvtpk(x3.x, x3.y);
            bfr[kk] = pu.s8;
        }

        // ---- GEMM1 (j-split): W2 frags from LDS, all 8 fo-blocks ----
#pragma unroll
        for (int s = 0; s < 8; ++s) {
            floatx4 a = *(const floatx4*)(EB2s + s * 16 + q * 4);  // CM-scaled
#pragma unroll
            for (int kk = 0; kk < 4; ++kk) {
                short8 wf = *(const short8*)(W2L + ((s * 4 + kk) * 64 + lane) * 8);
                a = __builtin_amdgcn_mfma_f32_16x16x32_bf16(wf, bfr[kk], a, 0, 0, 0);
            }
            floatx2 p0 = silu2s(mk2(a[0], a[1])) * f22;
            floatx2 p1 = silu2s(mk2(a[2], a[3])) * f22;
            ag2[2 * s]     += p0;
            ag2[2 * s + 1] += p1;
            *(uint2*)(msr + s * 16 + q * 4) =
                make_uint2(cvtpk(p0.x, p0.y), cvtpk(p1.x, p1.y));
        }
        __syncthreads();   // A: ms visible to all waves

        // ---- GEMM2 (fo-split): wcf in regs, B = ms frags, all 8 j-sets ----
#pragma unroll
        for (int jt = 0; jt < 8; ++jt) {
            const unsigned short* mr = ms + (jt * 16 + l15) * MSTRIDE;
            floatx4 a = c1b;
#pragma unroll
            for (int kk = 0; kk < 4; ++kk) {
                short8 bf = *(const short8*)(mr + kk * 32 + q * 8);
                a = __builtin_amdgcn_mfma_f32_16x16x32_bf16(wcf[kk], bf, a, 0, 0, 0);
            }
            floatx2 esv = silu2s(mk2(a[0], a[1])) * w2c2[0] +
                          silu2s(mk2(a[2], a[3])) * w2c2[1];
            float es = esv.x + esv.y;
            es += __shfl_xor(es, 16);
            es += __shfl_xor(es, 32);
            if (q == 0) embp[wave * F_ + jt * 16 + l15] = es;
        }
        __syncthreads();   // B: embp visible; guards ms for next tile

        // ---- coord accumulation for own j-rows (d/f2 still live) ----
        if (q == 0) {
            float e = 0.f;
#pragma unroll
            for (int wf = 0; wf < 8; ++wf) e += embp[wf * F_ + jl];
            float w = e * f2 * f2;
            cs0 += d0 * w;
            cs1 += d1 * w;
            cs2 += d2 * w;
        }
    }  // p

    // ---- in-wave reductions over j (l15) ----
#pragma unroll
    for (int t = 0; t < 16; ++t) {
        float vx = ag2[t].x, vy = ag2[t].y;
        vx += __shfl_xor(vx, 1); vx += __shfl_xor(vx, 2);
        vx += __shfl_xor(vx, 4); vx += __shfl_xor(vx, 8);
        vy += __shfl_xor(vy, 1); vy += __shfl_xor(vy, 2);
        vy += __shfl_xor(vy, 4); vy += __shfl_xor(vy, 8);
        ag2[t] = mk2(vx, vy);
    }
    cs0 += __shfl_xor(cs0, 1); cs0 += __shfl_xor(cs0, 2);
    cs0 += __shfl_xor(cs0, 4); cs0 += __shfl_xor(cs0, 8);
    cs1 += __shfl_xor(cs1, 1); cs1 += __shfl_xor(cs1, 2);
    cs1 += __shfl_xor(cs1, 4); cs1 += __shfl_xor(cs1, 8);
    cs2 += __shfl_xor(cs2, 1); cs2 += __shfl_xor(cs2, 2);
    cs2 += __shfl_xor(cs2, 4); cs2 += __shfl_xor(cs2, 8);

    __syncthreads();   // all waves past last ms read -> safe to alias
    if (l15 == 0) {
#pragma unroll
        for (int s = 0; s < 8; ++s) {
            floatx4 o = {ag2[2 * s].x, ag2[2 * s].y,
                         ag2[2 * s + 1].x, ag2[2 * s + 1].y};
            *(floatx4*)(aggp + wave * F_ + s * 16 + q * 4) = o;
        }
    }
    if (lane == 0) {
        csp[wave * 3 + 0] = cs0;
        csp[wave * 3 + 1] = cs1;
        csp[wave * 3 + 2] = cs2;
    }
    __syncthreads();
    if (tid < F_) {
        float s = 0.f;
#pragma unroll
        for (int w = 0; w < 8; ++w) s += aggp[w * F_ + tid];
        aggt[tid] = s * (mask_i * INVC);   // unwind CM
    }
    __syncthreads();
    // ---- node MLP layer 1: 512 threads, k-split in halves of 64 ----
    {
        const int col = tid & 127, q2 = tid >> 7;   // q2 0..3
        const int half = q2 & 1, kh = q2 >> 1;
        const float* W = nw1 + (half * 128 + kh * 64) * F_ + col;
        const float* src = half ? (aggt + kh * 64) : (hin + kh * 64);
        float s = 0.f;
#pragma unroll 8
        for (int k = 0; k < 64; ++k) s += src[k] * W[k * F_];
        if (half == 0) s *= mask_i;
        np[tid] = s;
    }
    __syncthreads();
    if (tid < F_)
        tl[tid] = fsilu(np[tid] + np[128 + tid] + np[256 + tid] +
                        np[384 + tid] + nb1[tid]);
    __syncthreads();
    if (tid < F_) {
        float s = nb2[tid];
#pragma unroll 8
        for (int k = 0; k < F_; ++k) s += tl[k] * nw2[k * F_ + tid];
        out_h[bi * F_ + tid] = (hin[tid] + s) * mask_i;
    } else if (tid < F_ + 3) {
        int d = tid - F_;
        float denom = mask_i * msum[b] + 1e-10f;
        float cm = (d == 0) ? cmi0 : ((d == 1) ? cmi1 : cmi2);
        float cst = 0.f;
#pragma unroll
        for (int w = 0; w < 8; ++w) cst += csp[w * 3 + d];
        out_coord[bi * 3 + d] = (cm + cst * __builtin_amdgcn_rcpf(denom)) * mask_i;
    }
}

// ---------------------------------------------------------------------------
extern "C" void kernel_launch(void* const* d_in, const int* in_sizes, int n_in,
                              void* d_out, int out_size, void* d_ws, size_t ws_size,
                              hipStream_t stream) {
    const float* h     = (const float*)d_in[0];
    const float* coord = (const float*)d_in[1];
    const float* mask  = (const float*)d_in[2];
    const float* ew1   = (const float*)d_in[3];
    const float* eb1   = (const float*)d_in[4];
    const float* ew2   = (const float*)d_in[5];
    const float* eb2   = (const float*)d_in[6];
    const float* nw1   = (const float*)d_in[7];
    const float* nb1   = (const float*)d_in[8];
    const float* nw2   = (const float*)d_in[9];
    const float* nb2   = (const float*)d_in[10];
    const float* cw1   = (const float*)d_in[11];
    const float* cb1   = (const float*)d_in[12];
    const float* cw2   = (const float*)d_in[13];

    float* Hs = (float*)d_ws;                                   // 131072 f32
    float* Ht = Hs + B_ * N_ * F_;                              // 131072 f32
    unsigned short* W2P = (unsigned short*)(Ht + B_ * N_ * F_); // 16384 u16
    unsigned short* WcP = W2P + F_ * F_;                        // 16384 u16
    float* msum = (float*)(WcP + F_ * F_);                      // 2 f32

    float* out_h = (float*)d_out;
    float* out_coord = out_h + B_ * N_ * F_;

    // raise dynamic-LDS cap once (75776 B > default 64 KB; gfx950 max 160 KB)
    static int attr_done = 0;
    if (!attr_done) {
        (void)hipFuncSetAttribute((const void*)egcl_main,
                                  hipFuncAttributeMaxDynamicSharedMemorySize,
                                  L_TOTAL);
        attr_done = 1;
    }

    egcl_prep<<<146, 256, 0, stream>>>(h, mask, ew1, ew2, cw1,
                                       Hs, Ht, W2P, WcP, msum);
    egcl_main<<<B_ * N_, 512, L_TOTAL, stream>>>(
        h, coord, mask, eb1, eb2, cb1, cw2, nw1, nb1, nw2, nb2, ew1,
        Hs, Ht, W2P, WcP, msum, out_h, out_coord);
}

// Round 6
// 178.433 us; speedup vs baseline: 1.3696x; 1.2118x over previous
//
#include <hip/hip_runtime.h>

// ============================================================================
// R18 = R13 (verified best: main 109us, total 177.6) + s_setprio(1) around
// MFMA clusters.
// Structural search is CLOSED by measurement:
//   R13 (fo-split, weights-in-regs, 24 bar, 4 w/SIMD)  = 109us  <- best
//   R15 (j-split, weights-in-LDS, 0 bar, 2 w/SIMD)     = 127us
//   R16 (j-split, weights-from-global -> spill)        = 176us
//   R17 (mixed, W2-in-LDS, 8 bar, 4 w/SIMD)            = 145us
// VALU-busy ~50us and MFMA-busy ~14us in ALL variants; stall tracks LDS
// bytes/tile. R13's weights-in-VGPR = zero weight traffic through LDS ->
// minimal DS-pipe load. Do NOT re-stream weights from LDS or global.
// setprio rationale: 4 independent blocks/CU at drifting phases (attn-like
// regime, T5 m191 +4-7%), not barrier-lockstep (m190 null).
//
// __launch_bounds__ 2nd-arg EMPIRICAL RULE (this toolchain, gfx950):
//   (256,4) -> 64-VGPR cap, catastrophic spill. NEVER set >= 4 here.
// ============================================================================

#define B_ 2
#define N_ 512
#define F_ 128
#define TJ 64       // j-rows per tile
#define MSTRIDE 136 // shorts per LDS row: 128 + 8 pad (16B-aligned rows)

#define CM   (-1.44269504088896340736f)   // -log2(e)
#define INVC (-0.69314718055994530942f)   // 1/CM = -ln2

typedef __attribute__((ext_vector_type(8))) short short8;
typedef __attribute__((ext_vector_type(4))) float floatx4;
typedef __attribute__((ext_vector_type(2))) float floatx2;

#if defined(__has_builtin)
#if __has_builtin(__builtin_amdgcn_exp2f)
#define EXP2F(x) __builtin_amdgcn_exp2f(x)
#endif
#endif
#ifndef EXP2F
#define EXP2F(x) __expf((x) * 0.69314718055994530942f)
#endif

__device__ __forceinline__ float fsilu(float x) {  // tail-only (128 calls/blk)
    float e = __expf(-x);
    return x * __builtin_amdgcn_rcpf(1.0f + e);
}
__device__ __forceinline__ floatx2 mk2(float a, float b) {
    floatx2 r; r.x = a; r.y = b; return r;
}
// y = CM*x. Returns CM*silu(x), pairwise. 1 trans + packable full-rate ops.
// Newton x2 from magic-constant reciprocal: rel err < 7e-6.
__device__ __forceinline__ floatx2 silu2s(floatx2 y) {
    floatx2 e;
    e.x = EXP2F(y.x);              // = exp(-x)
    e.y = EXP2F(y.y);
    floatx2 d = e + 1.0f;
    floatx2 r;
    r.x = __uint_as_float(0x7EF311C3u - __float_as_uint(d.x));
    r.y = __uint_as_float(0x7EF311C3u - __float_as_uint(d.y));
    r = r * (2.0f - d * r);
    r = r * (2.0f - d * r);
    return y * r;                  // y * sigmoid(x) = CM * silu(x)
}
// one v_cvt_pk_bf16_f32 replaces pack2's add+add+perm (gfx950, RNE)
__device__ __forceinline__ unsigned cvtpk(float lo, float hi) {
    unsigned r;
    asm("v_cvt_pk_bf16_f32 %0, %1, %2" : "=v"(r) : "v"(lo), "v"(hi));
    return r;
}
// pack two floats to bf16 pair via v_perm_b32 (prep kernel only)
__device__ __forceinline__ unsigned pack2(float a, float b) {
    return __builtin_amdgcn_perm(__float_as_uint(b) + 0x8000u,
                                 __float_as_uint(a) + 0x8000u, 0x07060302u);
}

// ---------------------------------------------------------------------------
// Prep: blocks [0,128): Hs/Ht (8 rows each, PRE-SCALED by CM);
//       [128,144): weight A-frag pack; [144,146): msum.
// ---------------------------------------------------------------------------
__global__ __launch_bounds__(256) void egcl_prep(
        const float* __restrict__ h, const float* __restrict__ mask,
        const float* __restrict__ ew1, const float* __restrict__ ew2,
        const float* __restrict__ cw1,
        float* __restrict__ Hs, float* __restrict__ Ht,
        unsigned short* __restrict__ W2P, unsigned short* __restrict__ WcP,
        float* __restrict__ msum) {
    __shared__ float sh[8][F_];
    const int blk = blockIdx.x, tid = threadIdx.x;
    if (blk < 128) {
        const int r0 = blk * 8;
        const int col = tid & 127, half = tid >> 7;
#pragma unroll
        for (int rr = 0; rr < 4; ++rr) {
            int row = rr * 2 + half;
            sh[row][col] = h[(r0 + row) * F_ + col] * mask[r0 + row];
        }
        __syncthreads();
        const float* W = ew1 + half * F_ * F_ + col;
        float acc[8] = {0.f, 0.f, 0.f, 0.f, 0.f, 0.f, 0.f, 0.f};
#pragma unroll 8
        for (int k = 0; k < F_; ++k) {
            float w = W[k * F_];
#pragma unroll
            for (int r = 0; r < 8; ++r) acc[r] += sh[r][k] * w;
        }
        float* dst = half ? Ht : Hs;
#pragma unroll
        for (int r = 0; r < 8; ++r) dst[(r0 + r) * F_ + col] = acc[r] * CM;
    } else if (blk < 144) {
        const int wsel = (blk - 128) >> 3;
        const int mt = (blk - 128) & 7;
        const float* src = wsel ? cw1 : ew2;
        unsigned short* dst = wsel ? WcP : W2P;
        const int ln = tid & 63, kk = tid >> 6;       // kk 0..3
        const int qq = ln >> 4, ll = ln & 15;
#pragma unroll
        for (int rep = 0; rep < 2; ++rep) {
            const int krow = kk * 32 + qq * 8 + rep * 4;
            float f0 = src[(krow + 0) * F_ + mt * 16 + ll];
            float f1 = src[(krow + 1) * F_ + mt * 16 + ll];
            float f2 = src[(krow + 2) * F_ + mt * 16 + ll];
            float f3 = src[(krow + 3) * F_ + mt * 16 + ll];
            uint2 u = make_uint2(pack2(f0, f1), pack2(f2, f3));
            *(uint2*)(dst + ((mt * 4 + kk) * 64 + ln) * 8 + rep * 4) = u;
        }
    } else {
        const int bb = blk - 144;
        float v = mask[bb * N_ + tid] + mask[bb * N_ + 256 + tid];
        v += __shfl_xor(v, 1);  v += __shfl_xor(v, 2);
        v += __shfl_xor(v, 4);  v += __shfl_xor(v, 8);
        v += __shfl_xor(v, 16); v += __shfl_xor(v, 32);
        const int wave = tid >> 6, lane = tid & 63;
        if (lane == 0) sh[0][wave] = v;
        __syncthreads();
        if (tid == 0) msum[bb] = sh[0][0] + sh[0][1] + sh[0][2] + sh[0][3];
    }
}

// LDS layout (bytes) — total 37888 (<= 40960 -> 4 blocks/CU preserved).
#define L_M1   0        // 64*136*2 = 17408
#define L_M    17408    // 17408
#define L_HB   34816    // 512
#define L_W1R  35328    // 512
#define L_EMBP 35840    // 4*64*4 = 1024
#define L_HIN  36864    // 512
#define L_RAD  37376    // 256  (radial*f2 per j-row of current tile)
#define L_F2   37632    // 256  (mask_i*mask_j per j-row)
#define L_TOTAL 37888
// Post-loop-only buffers aliased into m1s (dead after last GEMM1 read,
// ordered by sync2/sync3 of tile 7):
#define L_AGG  0        // 512
#define L_AGGT 512      // 512
#define L_TL   1024     // 512
#define L_NP   1536     // 1024
#define L_CSW  2560     // 32

// ---------------------------------------------------------------------------
// Main: 1024 blocks x 256 threads (4 waves); block = one (b,i). Wave wg owns
// fo slice [wg*32, wg*32+32) with weights in registers as MFMA A-operands.
// j in 8 tiles of 64 rows; 3 barriers per tile. All silu stages operate in
// CM-scaled space; W2P/WcP need no rescale (cancels).
// ---------------------------------------------------------------------------
__global__ __launch_bounds__(256, 2) void egcl_main(
        const float* __restrict__ h, const float* __restrict__ coord,
        const float* __restrict__ mask,
        const float* __restrict__ eb1, const float* __restrict__ eb2,
        const float* __restrict__ cb1, const float* __restrict__ cw2,
        const float* __restrict__ nw1, const float* __restrict__ nb1,
        const float* __restrict__ nw2, const float* __restrict__ nb2,
        const float* __restrict__ ew1,
        const float* __restrict__ Hs, const float* __restrict__ Ht,
        const unsigned short* __restrict__ W2P,
        const unsigned short* __restrict__ WcP,
        const float* __restrict__ msum,
        float* __restrict__ out_h, float* __restrict__ out_coord) {
    extern __shared__ char smem[];
    unsigned short* m1s = (unsigned short*)(smem + L_M1);
    unsigned short* ms  = (unsigned short*)(smem + L_M);
    float* HB    = (float*)(smem + L_HB);
    float* W1R   = (float*)(smem + L_W1R);
    float* embp  = (float*)(smem + L_EMBP);
    float* hin   = (float*)(smem + L_HIN);
    float* radl  = (float*)(smem + L_RAD);
    float* f2l   = (float*)(smem + L_F2);
    float* aggs  = (float*)(smem + L_AGG);   // aliases m1s (post-loop only)
    float* aggt  = (float*)(smem + L_AGGT);
    float* tl    = (float*)(smem + L_TL);
    float* np    = (float*)(smem + L_NP);
    float* csw   = (float*)(smem + L_CSW);

    const int tid  = threadIdx.x;
    const int wave = tid >> 6, lane = tid & 63;
    const int q = lane >> 4, l15 = lane & 15;
    const int wg = wave;                 // fo slice [wg*32, wg*32+32)
    const int bi = blockIdx.x;
    const int b  = bi >> 9;
    const float mask_i = mask[bi];

    // per-wave weight A-fragments (2 mt-slices of 16 fo each)
    short8 w2f[2][4], wcf[2][4];
#pragma unroll
    for (int s = 0; s < 2; ++s)
#pragma unroll
        for (int kk = 0; kk < 4; ++kk) {
            w2f[s][kk] = *(const short8*)(W2P + (((2 * wg + s) * 4 + kk) * 64 + lane) * 8);
            wcf[s][kk] = *(const short8*)(WcP + (((2 * wg + s) * 4 + kk) * 64 + lane) * 8);
        }
    // biases in CM-scaled space; w2c carries the 1/CM unwind
    floatx4 e2b[2], c1b[2];
    floatx2 w2c2[4];
#pragma unroll
    for (int s = 0; s < 2; ++s) {
        e2b[s] = (*(const floatx4*)(eb2 + wg * 32 + s * 16 + q * 4)) * CM;
        c1b[s] = (*(const floatx4*)(cb1 + wg * 32 + s * 16 + q * 4)) * CM;
    }
    {
        floatx4 w0 = *(const floatx4*)(cw2 + wg * 32 + 0 * 16 + q * 4);
        floatx4 w1 = *(const floatx4*)(cw2 + wg * 32 + 1 * 16 + q * 4);
        w2c2[0] = mk2(w0[0], w0[1]) * INVC;
        w2c2[1] = mk2(w0[2], w0[3]) * INVC;
        w2c2[2] = mk2(w1[0], w1[1]) * INVC;
        w2c2[3] = mk2(w1[2], w1[3]) * INVC;
    }

    if (tid < F_) {
        HB[tid]  = Ht[bi * F_ + tid] + CM * eb1[tid];   // Ht pre-scaled in prep
        W1R[tid] = CM * ew1[2 * F_ * F_ + tid];
        hin[tid] = h[bi * F_ + tid] * mask_i;
    }
    const float cmi0 = coord[bi * 3 + 0] * mask_i;
    const float cmi1 = coord[bi * 3 + 1] * mask_i;
    const float cmi2 = coord[bi * 3 + 2] * mask_i;
    // tile-0 radial/f2 precompute
    if (tid < TJ) {
        int jg = b * N_ + tid;
        float mj = mask[jg];
        float c0 = coord[jg * 3 + 0] * mj;
        float c1 = coord[jg * 3 + 1] * mj;
        float c2 = coord[jg * 3 + 2] * mj;
        float d0 = cmi0 - c0, d1 = cmi1 - c1, d2 = cmi2 - c2;
        float ff = mask_i * mj;
        radl[tid] = (d0 * d0 + d1 * d1 + d2 * d2) * ff;
        f2l[tid]  = ff;
    }
    __syncthreads();

    const int kseg = tid & 15, jq = tid >> 4;  // jq in [0,16)
    floatx2 hbk2[4], w1k2[4];
    {
        const floatx4* hp = (const floatx4*)(HB + kseg * 8);
        const floatx4* wp = (const floatx4*)(W1R + kseg * 8);
        floatx4 a = hp[0], bb2 = hp[1], cc = wp[0], dd = wp[1];
        hbk2[0] = mk2(a[0], a[1]);   hbk2[1] = mk2(a[2], a[3]);
        hbk2[2] = mk2(bb2[0], bb2[1]); hbk2[3] = mk2(bb2[2], bb2[3]);
        w1k2[0] = mk2(cc[0], cc[1]); w1k2[1] = mk2(cc[2], cc[3]);
        w1k2[2] = mk2(dd[0], dd[1]); w1k2[3] = mk2(dd[2], dd[3]);
    }
    floatx2 ag[4];
    ag[0] = mk2(0.f, 0.f); ag[1] = mk2(0.f, 0.f);
    ag[2] = mk2(0.f, 0.f); ag[3] = mk2(0.f, 0.f);
    float cs0 = 0.f, cs1 = 0.f, cs2 = 0.f;

    for (int p = 0; p < N_ / TJ; ++p) {
        // ---- m1 build: each thread covers 4 rows x 8 k (pairwise) ----
#pragma unroll
        for (int r = 0; r < 4; ++r) {
            int row = jq * 4 + r;
            int jg = b * N_ + p * TJ + row;
            float radm = radl[row];              // LDS broadcast
            floatx2 rr = mk2(radm, radm);
            const floatx4* hsp = (const floatx4*)(Hs + jg * F_ + kseg * 8);
            floatx4 h0 = hsp[0], h1 = hsp[1];
            floatx2 y0 = mk2(h0[0], h0[1]) + hbk2[0] + rr * w1k2[0];
            floatx2 y1 = mk2(h0[2], h0[3]) + hbk2[1] + rr * w1k2[1];
            floatx2 y2 = mk2(h1[0], h1[1]) + hbk2[2] + rr * w1k2[2];
            floatx2 y3 = mk2(h1[2], h1[3]) + hbk2[3] + rr * w1k2[3];
            floatx2 x0 = silu2s(y0), x1 = silu2s(y1);
            floatx2 x2 = silu2s(y2), x3 = silu2s(y3);
            union { short8 s8; unsigned u[4]; } pu;
            pu.u[0] = cvtpk(x0.x, x0.y); pu.u[1] = cvtpk(x1.x, x1.y);
            pu.u[2] = cvtpk(x2.x, x2.y); pu.u[3] = cvtpk(x3.x, x3.y);
            *(short8*)(m1s + row * MSTRIDE + kseg * 8) = pu.s8;
        }
        __syncthreads();
        // ---- GEMM1 (weights-in-regs as A) + epilogue1 ----
#pragma unroll
        for (int jt = 0; jt < 4; ++jt) {
            const int jrow = jt * 16 + l15;
            const unsigned short* m1r = m1s + jrow * MSTRIDE;
            floatx4 a0 = e2b[0], a1 = e2b[1];  // bias-init (CM-scaled)
            __builtin_amdgcn_s_setprio(1);
#pragma unroll
            for (int kk = 0; kk < 4; ++kk) {
                short8 bf = *(const short8*)(m1r + kk * 32 + q * 8);
                a0 = __builtin_amdgcn_mfma_f32_16x16x32_bf16(w2f[0][kk], bf, a0, 0, 0, 0);
                a1 = __builtin_amdgcn_mfma_f32_16x16x32_bf16(w2f[1][kk], bf, a1, 0, 0, 0);
            }
            __builtin_amdgcn_s_setprio(0);
            const float f2 = f2l[jrow];
            floatx2 f22 = mk2(f2, f2);
            floatx2 p0 = silu2s(mk2(a0[0], a0[1])) * f22;
            floatx2 p1 = silu2s(mk2(a0[2], a0[3])) * f22;
            floatx2 p2 = silu2s(mk2(a1[0], a1[1])) * f22;
            floatx2 p3 = silu2s(mk2(a1[2], a1[3])) * f22;
            ag[0] += p0; ag[1] += p1; ag[2] += p2; ag[3] += p3;
            unsigned short* mr = ms + jrow * MSTRIDE + wg * 32 + q * 4;
            *(uint2*)(mr)      = make_uint2(cvtpk(p0.x, p0.y), cvtpk(p1.x, p1.y));
            *(uint2*)(mr + 16) = make_uint2(cvtpk(p2.x, p2.y), cvtpk(p3.x, p3.y));
        }
        __syncthreads();
        // ---- GEMM2 + embed partials ----
#pragma unroll
        for (int jt = 0; jt < 4; ++jt) {
            const int jrow = jt * 16 + l15;
            const unsigned short* mr = ms + jrow * MSTRIDE;
            floatx4 a0 = c1b[0], a1 = c1b[1];
            __builtin_amdgcn_s_setprio(1);
#pragma unroll
            for (int kk = 0; kk < 4; ++kk) {
                short8 bf = *(const short8*)(mr + kk * 32 + q * 8);
                a0 = __builtin_amdgcn_mfma_f32_16x16x32_bf16(wcf[0][kk], bf, a0, 0, 0, 0);
                a1 = __builtin_amdgcn_mfma_f32_16x16x32_bf16(wcf[1][kk], bf, a1, 0, 0, 0);
            }
            __builtin_amdgcn_s_setprio(0);
            floatx2 esv = mk2(0.f, 0.f);
            esv += silu2s(mk2(a0[0], a0[1])) * w2c2[0];
            esv += silu2s(mk2(a0[2], a0[3])) * w2c2[1];
            esv += silu2s(mk2(a1[0], a1[1])) * w2c2[2];
            esv += silu2s(mk2(a1[2], a1[3])) * w2c2[3];
            float es = esv.x + esv.y;
            es += __shfl_xor(es, 16);
            es += __shfl_xor(es, 32);
            if (q == 0) embp[wg * 64 + jrow] = es;
        }
        // next-tile radial/f2 precompute (wave1; wave0 owns coord-accum).
        // Writes after sync2, reads after sync3 -> race-free, single buffer.
        if (p < N_ / TJ - 1 && wave == 1) {
            int jg = b * N_ + (p + 1) * TJ + lane;
            float mj = mask[jg];
            float c0 = coord[jg * 3 + 0] * mj;
            float c1 = coord[jg * 3 + 1] * mj;
            float c2 = coord[jg * 3 + 2] * mj;
            float d0 = cmi0 - c0, d1 = cmi1 - c1, d2 = cmi2 - c2;
            float ff = mask_i * mj;
            radl[lane] = (d0 * d0 + d1 * d1 + d2 * d2) * ff;
            f2l[lane]  = ff;
        }
        __syncthreads();
        // ---- coord accumulation (threads 0..63 = wave 0) ----
        if (tid < TJ) {
            float e = embp[tid] + embp[64 + tid] + embp[128 + tid] + embp[192 + tid];
            int jg = b * N_ + p * TJ + tid;
            float mj = mask[jg];
            float c0 = coord[jg * 3 + 0] * mj;
            float c1 = coord[jg * 3 + 1] * mj;
            float c2 = coord[jg * 3 + 2] * mj;
            float f2 = mask_i * mj;
            float w = e * f2 * f2;
            cs0 += (cmi0 - c0) * w;
            cs1 += (cmi1 - c1) * w;
            cs2 += (cmi2 - c2) * w;
        }
    }  // p

    // ---- reductions (agg still CM-scaled; unwound at aggt) ----
    float agf[8] = {ag[0].x, ag[0].y, ag[1].x, ag[1].y,
                    ag[2].x, ag[2].y, ag[3].x, ag[3].y};
#pragma unroll
    for (int rg = 0; rg < 8; ++rg) {
        float v = agf[rg];
        v += __shfl_xor(v, 1); v += __shfl_xor(v, 2);
        v += __shfl_xor(v, 4); v += __shfl_xor(v, 8);
        agf[rg] = v;
    }
    if (l15 == 0) {
        floatx4 o0 = {agf[0], agf[1], agf[2], agf[3]};
        floatx4 o1 = {agf[4], agf[5], agf[6], agf[7]};
        *(floatx4*)(aggs + wg * 32 + q * 4)      = o0;
        *(floatx4*)(aggs + wg * 32 + 16 + q * 4) = o1;
    }
    if (wave == 0) {
        cs0 += __shfl_xor(cs0, 1); cs0 += __shfl_xor(cs0, 2);
        cs0 += __shfl_xor(cs0, 4); cs0 += __shfl_xor(cs0, 8);
        cs0 += __shfl_xor(cs0, 16); cs0 += __shfl_xor(cs0, 32);
        cs1 += __shfl_xor(cs1, 1); cs1 += __shfl_xor(cs1, 2);
        cs1 += __shfl_xor(cs1, 4); cs1 += __shfl_xor(cs1, 8);
        cs1 += __shfl_xor(cs1, 16); cs1 += __shfl_xor(cs1, 32);
        cs2 += __shfl_xor(cs2, 1); cs2 += __shfl_xor(cs2, 2);
        cs2 += __shfl_xor(cs2, 4); cs2 += __shfl_xor(cs2, 8);
        cs2 += __shfl_xor(cs2, 16); cs2 += __shfl_xor(cs2, 32);
        if (lane == 0) {
            csw[0] = cs0; csw[1] = cs1; csw[2] = cs2;
        }
    }
    __syncthreads();
    if (tid < F_) aggt[tid] = aggs[tid] * (mask_i * INVC);  // unwind CM
    __syncthreads();
    // ---- node MLP layer 1 ----
    {
        int half = tid >> 7, col = tid & 127;
        const float* W = nw1 + half * 128 * F_ + col;
        float s = 0.f;
        if (half == 0) {
#pragma unroll 8
            for (int k = 0; k < F_; ++k) s += hin[k] * W[k * F_];
            s *= mask_i;
        } else {
#pragma unroll 8
            for (int k = 0; k < F_; ++k) s += aggt[k] * W[k * F_];
        }
        np[tid] = s;
    }
    __syncthreads();
    if (tid < F_) tl[tid] = fsilu(np[tid] + np[128 + tid] + nb1[tid]);
    __syncthreads();
    if (tid < F_) {
        float s = nb2[tid];
#pragma unroll 8
        for (int k = 0; k < F_; ++k) s += tl[k] * nw2[k * F_ + tid];
        out_h[bi * F_ + tid] = (hin[tid] + s) * mask_i;
    } else if (tid < F_ + 3) {
        int d = tid - F_;
        float denom = mask_i * msum[b] + 1e-10f;
        float cm = (d == 0) ? cmi0 : ((d == 1) ? cmi1 : cmi2);
        out_coord[bi * 3 + d] = (cm + csw[d] * __builtin_amdgcn_rcpf(denom)) * mask_i;
    }
}

// ---------------------------------------------------------------------------
extern "C" void kernel_launch(void* const* d_in, const int* in_sizes, int n_in,
                              void* d_out, int out_size, void* d_ws, size_t ws_size,
                              hipStream_t stream) {
    const float* h     = (const float*)d_in[0];
    const float* coord = (const float*)d_in[1];
    const float* mask  = (const float*)d_in[2];
    const float* ew1   = (const float*)d_in[3];
    const float* eb1   = (const float*)d_in[4];
    const float* ew2   = (const float*)d_in[5];
    const float* eb2   = (const float*)d_in[6];
    const float* nw1   = (const float*)d_in[7];
    const float* nb1   = (const float*)d_in[8];
    const float* nw2   = (const float*)d_in[9];
    const float* nb2   = (const float*)d_in[10];
    const float* cw1   = (const float*)d_in[11];
    const float* cb1   = (const float*)d_in[12];
    const float* cw2   = (const float*)d_in[13];

    float* Hs = (float*)d_ws;                                   // 131072 f32
    float* Ht = Hs + B_ * N_ * F_;                              // 131072 f32
    unsigned short* W2P = (unsigned short*)(Ht + B_ * N_ * F_); // 16384 u16
    unsigned short* WcP = W2P + F_ * F_;                        // 16384 u16
    float* msum = (float*)(WcP + F_ * F_);                      // 2 f32

    float* out_h = (float*)d_out;
    float* out_coord = out_h + B_ * N_ * F_;

    egcl_prep<<<146, 256, 0, stream>>>(h, mask, ew1, ew2, cw1,
                                       Hs, Ht, W2P, WcP, msum);
    egcl_main<<<B_ * N_, 256, L_TOTAL, stream>>>(
        h, coord, mask, eb1, eb2, cb1, cw2, nw1, nb1, nw2, nb2, ew1,
        Hs, Ht, W2P, WcP, msum, out_h, out_coord);
}

// Round 7
// 177.340 us; speedup vs baseline: 1.3780x; 1.0062x over previous
//
#include <hip/hip_runtime.h>

// ============================================================================
// R19 (FINAL) = R13 verbatim — best measured: total 177.63 µs, main ~109 µs.
// R18's setprio variant measured +0.8 µs (null-to-negative; lockstep waves =
// m190 regime) -> reverted.
//
// Closed search (this session + previous):
//   R7-R11: barrier count 3->2->1, TJ sweep, 512t     -> 113-128 µs (null)
//   R13: exp2-silu + NR-rcp + cvt_pk + radial-LDS     -> 109 µs (WIN, -11 busy)
//   R15: zero-barrier j-split @2 w/SIMD (weights LDS) -> 127 µs (TLP loss)
//   R16: weights-from-global in loop                  -> 176 µs (spill, 47MB WRITE)
//   R17: mixed split @4 w/SIMD, W2-in-LDS             -> 145 µs (LDS re-stream)
//   R18: R13+setprio                                  -> 112 µs (null)
// Plateau structure: VALU-busy ~48 µs is algorithmic (201M silu, computed
// exactly once each); MFMA ~14 µs = bf16 floor; rest is dependency-latency
// stall at 4 waves/SIMD (VGPR=104 and LDS=37.9KB both cap occupancy; every
// TLP/pipeline/priority intervention measured null or worse). Total-vs-main
// gap ~65 µs is prep+launch+harness overhead.
//
// __launch_bounds__ 2nd-arg EMPIRICAL RULE (this toolchain, gfx950):
//   (256,4)/(512,4) -> 64-VGPR cap, catastrophic spill. NEVER set >= 4.
// Weight operands MUST be in VGPRs (A-frags); never re-stream from LDS or
// global inside the loop (R15/R16/R17 evidence).
// ============================================================================

#define B_ 2
#define N_ 512
#define F_ 128
#define TJ 64       // j-rows per tile
#define MSTRIDE 136 // shorts per LDS row: 128 + 8 pad (16B-aligned rows)

#define CM   (-1.44269504088896340736f)   // -log2(e)
#define INVC (-0.69314718055994530942f)   // 1/CM = -ln2

typedef __attribute__((ext_vector_type(8))) short short8;
typedef __attribute__((ext_vector_type(4))) float floatx4;
typedef __attribute__((ext_vector_type(2))) float floatx2;

#if defined(__has_builtin)
#if __has_builtin(__builtin_amdgcn_exp2f)
#define EXP2F(x) __builtin_amdgcn_exp2f(x)
#endif
#endif
#ifndef EXP2F
#define EXP2F(x) __expf((x) * 0.69314718055994530942f)
#endif

__device__ __forceinline__ float fsilu(float x) {  // tail-only (128 calls/blk)
    float e = __expf(-x);
    return x * __builtin_amdgcn_rcpf(1.0f + e);
}
__device__ __forceinline__ floatx2 mk2(float a, float b) {
    floatx2 r; r.x = a; r.y = b; return r;
}
// y = CM*x. Returns CM*silu(x), pairwise. 1 trans + packable full-rate ops.
// Newton x2 from magic-constant reciprocal: rel err < 7e-6.
__device__ __forceinline__ floatx2 silu2s(floatx2 y) {
    floatx2 e;
    e.x = EXP2F(y.x);              // = exp(-x)
    e.y = EXP2F(y.y);
    floatx2 d = e + 1.0f;
    floatx2 r;
    r.x = __uint_as_float(0x7EF311C3u - __float_as_uint(d.x));
    r.y = __uint_as_float(0x7EF311C3u - __float_as_uint(d.y));
    r = r * (2.0f - d * r);
    r = r * (2.0f - d * r);
    return y * r;                  // y * sigmoid(x) = CM * silu(x)
}
// one v_cvt_pk_bf16_f32 replaces pack2's add+add+perm (gfx950, RNE)
__device__ __forceinline__ unsigned cvtpk(float lo, float hi) {
    unsigned r;
    asm("v_cvt_pk_bf16_f32 %0, %1, %2" : "=v"(r) : "v"(lo), "v"(hi));
    return r;
}
// pack two floats to bf16 pair via v_perm_b32 (prep kernel only)
__device__ __forceinline__ unsigned pack2(float a, float b) {
    return __builtin_amdgcn_perm(__float_as_uint(b) + 0x8000u,
                                 __float_as_uint(a) + 0x8000u, 0x07060302u);
}

// ---------------------------------------------------------------------------
// Prep: blocks [0,128): Hs/Ht (8 rows each, PRE-SCALED by CM);
//       [128,144): weight A-frag pack; [144,146): msum.
// ---------------------------------------------------------------------------
__global__ __launch_bounds__(256) void egcl_prep(
        const float* __restrict__ h, const float* __restrict__ mask,
        const float* __restrict__ ew1, const float* __restrict__ ew2,
        const float* __restrict__ cw1,
        float* __restrict__ Hs, float* __restrict__ Ht,
        unsigned short* __restrict__ W2P, unsigned short* __restrict__ WcP,
        float* __restrict__ msum) {
    __shared__ float sh[8][F_];
    const int blk = blockIdx.x, tid = threadIdx.x;
    if (blk < 128) {
        const int r0 = blk * 8;
        const int col = tid & 127, half = tid >> 7;
#pragma unroll
        for (int rr = 0; rr < 4; ++rr) {
            int row = rr * 2 + half;
            sh[row][col] = h[(r0 + row) * F_ + col] * mask[r0 + row];
        }
        __syncthreads();
        const float* W = ew1 + half * F_ * F_ + col;
        float acc[8] = {0.f, 0.f, 0.f, 0.f, 0.f, 0.f, 0.f, 0.f};
#pragma unroll 8
        for (int k = 0; k < F_; ++k) {
            float w = W[k * F_];
#pragma unroll
            for (int r = 0; r < 8; ++r) acc[r] += sh[r][k] * w;
        }
        float* dst = half ? Ht : Hs;
#pragma unroll
        for (int r = 0; r < 8; ++r) dst[(r0 + r) * F_ + col] = acc[r] * CM;
    } else if (blk < 144) {
        const int wsel = (blk - 128) >> 3;
        const int mt = (blk - 128) & 7;
        const float* src = wsel ? cw1 : ew2;
        unsigned short* dst = wsel ? WcP : W2P;
        const int ln = tid & 63, kk = tid >> 6;       // kk 0..3
        const int qq = ln >> 4, ll = ln & 15;
#pragma unroll
        for (int rep = 0; rep < 2; ++rep) {
            const int krow = kk * 32 + qq * 8 + rep * 4;
            float f0 = src[(krow + 0) * F_ + mt * 16 + ll];
            float f1 = src[(krow + 1) * F_ + mt * 16 + ll];
            float f2 = src[(krow + 2) * F_ + mt * 16 + ll];
            float f3 = src[(krow + 3) * F_ + mt * 16 + ll];
            uint2 u = make_uint2(pack2(f0, f1), pack2(f2, f3));
            *(uint2*)(dst + ((mt * 4 + kk) * 64 + ln) * 8 + rep * 4) = u;
        }
    } else {
        const int bb = blk - 144;
        float v = mask[bb * N_ + tid] + mask[bb * N_ + 256 + tid];
        v += __shfl_xor(v, 1);  v += __shfl_xor(v, 2);
        v += __shfl_xor(v, 4);  v += __shfl_xor(v, 8);
        v += __shfl_xor(v, 16); v += __shfl_xor(v, 32);
        const int wave = tid >> 6, lane = tid & 63;
        if (lane == 0) sh[0][wave] = v;
        __syncthreads();
        if (tid == 0) msum[bb] = sh[0][0] + sh[0][1] + sh[0][2] + sh[0][3];
    }
}

// LDS layout (bytes) — total 37888 (<= 40960 -> 4 blocks/CU preserved).
#define L_M1   0        // 64*136*2 = 17408
#define L_M    17408    // 17408
#define L_HB   34816    // 512
#define L_W1R  35328    // 512
#define L_EMBP 35840    // 4*64*4 = 1024
#define L_HIN  36864    // 512
#define L_RAD  37376    // 256  (radial*f2 per j-row of current tile)
#define L_F2   37632    // 256  (mask_i*mask_j per j-row)
#define L_TOTAL 37888
// Post-loop-only buffers aliased into m1s (dead after last GEMM1 read,
// ordered by sync2/sync3 of tile 7):
#define L_AGG  0        // 512
#define L_AGGT 512      // 512
#define L_TL   1024     // 512
#define L_NP   1536     // 1024
#define L_CSW  2560     // 32

// ---------------------------------------------------------------------------
// Main: 1024 blocks x 256 threads (4 waves); block = one (b,i). Wave wg owns
// fo slice [wg*32, wg*32+32) with weights in registers as MFMA A-operands.
// j in 8 tiles of 64 rows; 3 barriers per tile. All silu stages operate in
// CM-scaled space; W2P/WcP need no rescale (cancels).
// ---------------------------------------------------------------------------
__global__ __launch_bounds__(256, 2) void egcl_main(
        const float* __restrict__ h, const float* __restrict__ coord,
        const float* __restrict__ mask,
        const float* __restrict__ eb1, const float* __restrict__ eb2,
        const float* __restrict__ cb1, const float* __restrict__ cw2,
        const float* __restrict__ nw1, const float* __restrict__ nb1,
        const float* __restrict__ nw2, const float* __restrict__ nb2,
        const float* __restrict__ ew1,
        const float* __restrict__ Hs, const float* __restrict__ Ht,
        const unsigned short* __restrict__ W2P,
        const unsigned short* __restrict__ WcP,
        const float* __restrict__ msum,
        float* __restrict__ out_h, float* __restrict__ out_coord) {
    extern __shared__ char smem[];
    unsigned short* m1s = (unsigned short*)(smem + L_M1);
    unsigned short* ms  = (unsigned short*)(smem + L_M);
    float* HB    = (float*)(smem + L_HB);
    float* W1R   = (float*)(smem + L_W1R);
    float* embp  = (float*)(smem + L_EMBP);
    float* hin   = (float*)(smem + L_HIN);
    float* radl  = (float*)(smem + L_RAD);
    float* f2l   = (float*)(smem + L_F2);
    float* aggs  = (float*)(smem + L_AGG);   // aliases m1s (post-loop only)
    float* aggt  = (float*)(smem + L_AGGT);
    float* tl    = (float*)(smem + L_TL);
    float* np    = (float*)(smem + L_NP);
    float* csw   = (float*)(smem + L_CSW);

    const int tid  = threadIdx.x;
    const int wave = tid >> 6, lane = tid & 63;
    const int q = lane >> 4, l15 = lane & 15;
    const int wg = wave;                 // fo slice [wg*32, wg*32+32)
    const int bi = blockIdx.x;
    const int b  = bi >> 9;
    const float mask_i = mask[bi];

    // per-wave weight A-fragments (2 mt-slices of 16 fo each)
    short8 w2f[2][4], wcf[2][4];
#pragma unroll
    for (int s = 0; s < 2; ++s)
#pragma unroll
        for (int kk = 0; kk < 4; ++kk) {
            w2f[s][kk] = *(const short8*)(W2P + (((2 * wg + s) * 4 + kk) * 64 + lane) * 8);
            wcf[s][kk] = *(const short8*)(WcP + (((2 * wg + s) * 4 + kk) * 64 + lane) * 8);
        }
    // biases in CM-scaled space; w2c carries the 1/CM unwind
    floatx4 e2b[2], c1b[2];
    floatx2 w2c2[4];
#pragma unroll
    for (int s = 0; s < 2; ++s) {
        e2b[s] = (*(const floatx4*)(eb2 + wg * 32 + s * 16 + q * 4)) * CM;
        c1b[s] = (*(const floatx4*)(cb1 + wg * 32 + s * 16 + q * 4)) * CM;
    }
    {
        floatx4 w0 = *(const floatx4*)(cw2 + wg * 32 + 0 * 16 + q * 4);
        floatx4 w1 = *(const floatx4*)(cw2 + wg * 32 + 1 * 16 + q * 4);
        w2c2[0] = mk2(w0[0], w0[1]) * INVC;
        w2c2[1] = mk2(w0[2], w0[3]) * INVC;
        w2c2[2] = mk2(w1[0], w1[1]) * INVC;
        w2c2[3] = mk2(w1[2], w1[3]) * INVC;
    }

    if (tid < F_) {
        HB[tid]  = Ht[bi * F_ + tid] + CM * eb1[tid];   // Ht pre-scaled in prep
        W1R[tid] = CM * ew1[2 * F_ * F_ + tid];
        hin[tid] = h[bi * F_ + tid] * mask_i;
    }
    const float cmi0 = coord[bi * 3 + 0] * mask_i;
    const float cmi1 = coord[bi * 3 + 1] * mask_i;
    const float cmi2 = coord[bi * 3 + 2] * mask_i;
    // tile-0 radial/f2 precompute
    if (tid < TJ) {
        int jg = b * N_ + tid;
        float mj = mask[jg];
        float c0 = coord[jg * 3 + 0] * mj;
        float c1 = coord[jg * 3 + 1] * mj;
        float c2 = coord[jg * 3 + 2] * mj;
        float d0 = cmi0 - c0, d1 = cmi1 - c1, d2 = cmi2 - c2;
        float ff = mask_i * mj;
        radl[tid] = (d0 * d0 + d1 * d1 + d2 * d2) * ff;
        f2l[tid]  = ff;
    }
    __syncthreads();

    const int kseg = tid & 15, jq = tid >> 4;  // jq in [0,16)
    floatx2 hbk2[4], w1k2[4];
    {
        const floatx4* hp = (const floatx4*)(HB + kseg * 8);
        const floatx4* wp = (const floatx4*)(W1R + kseg * 8);
        floatx4 a = hp[0], bb2 = hp[1], cc = wp[0], dd = wp[1];
        hbk2[0] = mk2(a[0], a[1]);   hbk2[1] = mk2(a[2], a[3]);
        hbk2[2] = mk2(bb2[0], bb2[1]); hbk2[3] = mk2(bb2[2], bb2[3]);
        w1k2[0] = mk2(cc[0], cc[1]); w1k2[1] = mk2(cc[2], cc[3]);
        w1k2[2] = mk2(dd[0], dd[1]); w1k2[3] = mk2(dd[2], dd[3]);
    }
    floatx2 ag[4];
    ag[0] = mk2(0.f, 0.f); ag[1] = mk2(0.f, 0.f);
    ag[2] = mk2(0.f, 0.f); ag[3] = mk2(0.f, 0.f);
    float cs0 = 0.f, cs1 = 0.f, cs2 = 0.f;

    for (int p = 0; p < N_ / TJ; ++p) {
        // ---- m1 build: each thread covers 4 rows x 8 k (pairwise) ----
#pragma unroll
        for (int r = 0; r < 4; ++r) {
            int row = jq * 4 + r;
            int jg = b * N_ + p * TJ + row;
            float radm = radl[row];              // LDS broadcast
            floatx2 rr = mk2(radm, radm);
            const floatx4* hsp = (const floatx4*)(Hs + jg * F_ + kseg * 8);
            floatx4 h0 = hsp[0], h1 = hsp[1];
            floatx2 y0 = mk2(h0[0], h0[1]) + hbk2[0] + rr * w1k2[0];
            floatx2 y1 = mk2(h0[2], h0[3]) + hbk2[1] + rr * w1k2[1];
            floatx2 y2 = mk2(h1[0], h1[1]) + hbk2[2] + rr * w1k2[2];
            floatx2 y3 = mk2(h1[2], h1[3]) + hbk2[3] + rr * w1k2[3];
            floatx2 x0 = silu2s(y0), x1 = silu2s(y1);
            floatx2 x2 = silu2s(y2), x3 = silu2s(y3);
            union { short8 s8; unsigned u[4]; } pu;
            pu.u[0] = cvtpk(x0.x, x0.y); pu.u[1] = cvtpk(x1.x, x1.y);
            pu.u[2] = cvtpk(x2.x, x2.y); pu.u[3] = cvtpk(x3.x, x3.y);
            *(short8*)(m1s + row * MSTRIDE + kseg * 8) = pu.s8;
        }
        __syncthreads();
        // ---- GEMM1 (weights-in-regs as A) + epilogue1 ----
#pragma unroll
        for (int jt = 0; jt < 4; ++jt) {
            const int jrow = jt * 16 + l15;
            const unsigned short* m1r = m1s + jrow * MSTRIDE;
            floatx4 a0 = e2b[0], a1 = e2b[1];  // bias-init (CM-scaled)
#pragma unroll
            for (int kk = 0; kk < 4; ++kk) {
                short8 bf = *(const short8*)(m1r + kk * 32 + q * 8);
                a0 = __builtin_amdgcn_mfma_f32_16x16x32_bf16(w2f[0][kk], bf, a0, 0, 0, 0);
                a1 = __builtin_amdgcn_mfma_f32_16x16x32_bf16(w2f[1][kk], bf, a1, 0, 0, 0);
            }
            const float f2 = f2l[jrow];
            floatx2 f22 = mk2(f2, f2);
            floatx2 p0 = silu2s(mk2(a0[0], a0[1])) * f22;
            floatx2 p1 = silu2s(mk2(a0[2], a0[3])) * f22;
            floatx2 p2 = silu2s(mk2(a1[0], a1[1])) * f22;
            floatx2 p3 = silu2s(mk2(a1[2], a1[3])) * f22;
            ag[0] += p0; ag[1] += p1; ag[2] += p2; ag[3] += p3;
            unsigned short* mr = ms + jrow * MSTRIDE + wg * 32 + q * 4;
            *(uint2*)(mr)      = make_uint2(cvtpk(p0.x, p0.y), cvtpk(p1.x, p1.y));
            *(uint2*)(mr + 16) = make_uint2(cvtpk(p2.x, p2.y), cvtpk(p3.x, p3.y));
        }
        __syncthreads();
        // ---- GEMM2 + embed partials ----
#pragma unroll
        for (int jt = 0; jt < 4; ++jt) {
            const int jrow = jt * 16 + l15;
            const unsigned short* mr = ms + jrow * MSTRIDE;
            floatx4 a0 = c1b[0], a1 = c1b[1];
#pragma unroll
            for (int kk = 0; kk < 4; ++kk) {
                short8 bf = *(const short8*)(mr + kk * 32 + q * 8);
                a0 = __builtin_amdgcn_mfma_f32_16x16x32_bf16(wcf[0][kk], bf, a0, 0, 0, 0);
                a1 = __builtin_amdgcn_mfma_f32_16x16x32_bf16(wcf[1][kk], bf, a1, 0, 0, 0);
            }
            floatx2 esv = mk2(0.f, 0.f);
            esv += silu2s(mk2(a0[0], a0[1])) * w2c2[0];
            esv += silu2s(mk2(a0[2], a0[3])) * w2c2[1];
            esv += silu2s(mk2(a1[0], a1[1])) * w2c2[2];
            esv += silu2s(mk2(a1[2], a1[3])) * w2c2[3];
            float es = esv.x + esv.y;
            es += __shfl_xor(es, 16);
            es += __shfl_xor(es, 32);
            if (q == 0) embp[wg * 64 + jrow] = es;
        }
        // next-tile radial/f2 precompute (wave1; wave0 owns coord-accum).
        // Writes after sync2, reads after sync3 -> race-free, single buffer.
        if (p < N_ / TJ - 1 && wave == 1) {
            int jg = b * N_ + (p + 1) * TJ + lane;
            float mj = mask[jg];
            float c0 = coord[jg * 3 + 0] * mj;
            float c1 = coord[jg * 3 + 1] * mj;
            float c2 = coord[jg * 3 + 2] * mj;
            float d0 = cmi0 - c0, d1 = cmi1 - c1, d2 = cmi2 - c2;
            float ff = mask_i * mj;
            radl[lane] = (d0 * d0 + d1 * d1 + d2 * d2) * ff;
            f2l[lane]  = ff;
        }
        __syncthreads();
        // ---- coord accumulation (threads 0..63 = wave 0) ----
        if (tid < TJ) {
            float e = embp[tid] + embp[64 + tid] + embp[128 + tid] + embp[192 + tid];
            int jg = b * N_ + p * TJ + tid;
            float mj = mask[jg];
            float c0 = coord[jg * 3 + 0] * mj;
            float c1 = coord[jg * 3 + 1] * mj;
            float c2 = coord[jg * 3 + 2] * mj;
            float f2 = mask_i * mj;
            float w = e * f2 * f2;
            cs0 += (cmi0 - c0) * w;
            cs1 += (cmi1 - c1) * w;
            cs2 += (cmi2 - c2) * w;
        }
    }  // p

    // ---- reductions (agg still CM-scaled; unwound at aggt) ----
    float agf[8] = {ag[0].x, ag[0].y, ag[1].x, ag[1].y,
                    ag[2].x, ag[2].y, ag[3].x, ag[3].y};
#pragma unroll
    for (int rg = 0; rg < 8; ++rg) {
        float v = agf[rg];
        v += __shfl_xor(v, 1); v += __shfl_xor(v, 2);
        v += __shfl_xor(v, 4); v += __shfl_xor(v, 8);
        agf[rg] = v;
    }
    if (l15 == 0) {
        floatx4 o0 = {agf[0], agf[1], agf[2], agf[3]};
        floatx4 o1 = {agf[4], agf[5], agf[6], agf[7]};
        *(floatx4*)(aggs + wg * 32 + q * 4)      = o0;
        *(floatx4*)(aggs + wg * 32 + 16 + q * 4) = o1;
    }
    if (wave == 0) {
        cs0 += __shfl_xor(cs0, 1); cs0 += __shfl_xor(cs0, 2);
        cs0 += __shfl_xor(cs0, 4); cs0 += __shfl_xor(cs0, 8);
        cs0 += __shfl_xor(cs0, 16); cs0 += __shfl_xor(cs0, 32);
        cs1 += __shfl_xor(cs1, 1); cs1 += __shfl_xor(cs1, 2);
        cs1 += __shfl_xor(cs1, 4); cs1 += __shfl_xor(cs1, 8);
        cs1 += __shfl_xor(cs1, 16); cs1 += __shfl_xor(cs1, 32);
        cs2 += __shfl_xor(cs2, 1); cs2 += __shfl_xor(cs2, 2);
        cs2 += __shfl_xor(cs2, 4); cs2 += __shfl_xor(cs2, 8);
        cs2 += __shfl_xor(cs2, 16); cs2 += __shfl_xor(cs2, 32);
        if (lane == 0) {
            csw[0] = cs0; csw[1] = cs1; csw[2] = cs2;
        }
    }
    __syncthreads();
    if (tid < F_) aggt[tid] = aggs[tid] * (mask_i * INVC);  // unwind CM
    __syncthreads();
    // ---- node MLP layer 1 ----
    {
        int half = tid >> 7, col = tid & 127;
        const float* W = nw1 + half * 128 * F_ + col;
        float s = 0.f;
        if (half == 0) {
#pragma unroll 8
            for (int k = 0; k < F_; ++k) s += hin[k] * W[k * F_];
            s *= mask_i;
        } else {
#pragma unroll 8
            for (int k = 0; k < F_; ++k) s += aggt[k] * W[k * F_];
        }
        np[tid] = s;
    }
    __syncthreads();
    if (tid < F_) tl[tid] = fsilu(np[tid] + np[128 + tid] + nb1[tid]);
    __syncthreads();
    if (tid < F_) {
        float s = nb2[tid];
#pragma unroll 8
        for (int k = 0; k < F_; ++k) s += tl[k] * nw2[k * F_ + tid];
        out_h[bi * F_ + tid] = (hin[tid] + s) * mask_i;
    } else if (tid < F_ + 3) {
        int d = tid - F_;
        float denom = mask_i * msum[b] + 1e-10f;
        float cm = (d == 0) ? cmi0 : ((d == 1) ? cmi1 : cmi2);
        out_coord[bi * 3 + d] = (cm + csw[d] * __builtin_amdgcn_rcpf(denom)) * mask_i;
    }
}

// ---------------------------------------------------------------------------
extern "C" void kernel_launch(void* const* d_in, const int* in_sizes, int n_in,
                              void* d_out, int out_size, void* d_ws, size_t ws_size,
                              hipStream_t stream) {
    const float* h     = (const float*)d_in[0];
    const float* coord = (const float*)d_in[1];
    const float* mask  = (const float*)d_in[2];
    const float* ew1   = (const float*)d_in[3];
    const float* eb1   = (const float*)d_in[4];
    const float* ew2   = (const float*)d_in[5];
    const float* eb2   = (const float*)d_in[6];
    const float* nw1   = (const float*)d_in[7];
    const float* nb1   = (const float*)d_in[8];
    const float* nw2   = (const float*)d_in[9];
    const float* nb2   = (const float*)d_in[10];
    const float* cw1   = (const float*)d_in[11];
    const float* cb1   = (const float*)d_in[12];
    const float* cw2   = (const float*)d_in[13];

    float* Hs = (float*)d_ws;                                   // 131072 f32
    float* Ht = Hs + B_ * N_ * F_;                              // 131072 f32
    unsigned short* W2P = (unsigned short*)(Ht + B_ * N_ * F_); // 16384 u16
    unsigned short* WcP = W2P + F_ * F_;                        // 16384 u16
    float* msum = (float*)(WcP + F_ * F_);                      // 2 f32

    float* out_h = (float*)d_out;
    float* out_coord = out_h + B_ * N_ * F_;

    egcl_prep<<<146, 256, 0, stream>>>(h, mask, ew1, ew2, cw1,
                                       Hs, Ht, W2P, WcP, msum);
    egcl_main<<<B_ * N_, 256, L_TOTAL, stream>>>(
        h, coord, mask, eb1, eb2, cb1, cw2, nw1, nb1, nw2, nb2, ew1,
        Hs, Ht, W2P, WcP, msum, out_h, out_coord);
}